// Round 1
// baseline (22361.263 us; speedup 1.0000x reference)
//
#include <hip/hip_runtime.h>
#include <stdint.h>

// SequentialFeedForward: autoregressive 6-layer MLP, L=2048 steps.
// Latency-bound dataflow kernel: 256 persistent workgroups (1/CU), each owns
// 8 rows of every dense layer. Activations exchanged as self-tagged
// (tag<<16)|fp16 words via device-scope relaxed atomics; 4 hops/step.
// fp16 weights + fp32 accumulation (v_dot2_f32_f16); est. error ~1e-3.

typedef uint32_t u32;
typedef _Float16 half_t;
typedef _Float16 half2_t __attribute__((ext_vector_type(2)));

#define L_SEQ 2048
#define WIDTH 2048
#define WS    32
#define NAA   21
#define INS   704   // WS*NAA + WS

__device__ __forceinline__ float h2f(u32 b){
  union { unsigned short u; half_t h; } c; c.u = (unsigned short)(b & 0xffffu);
  return (float)c.h;
}
__device__ __forceinline__ u32 f2h(float f){
  union { unsigned short u; half_t h; } c; c.h = (half_t)f;
  return (u32)c.u;
}
__device__ __forceinline__ float fdot2f(u32 a, u32 b, float c){
#if __has_builtin(__builtin_amdgcn_fdot2)
  union { u32 u; half2_t v; } ca, cb; ca.u = a; cb.u = b;
  return __builtin_amdgcn_fdot2(ca.v, cb.v, c, false);
#else
  return c + h2f(a)*h2f(b) + h2f(a>>16)*h2f(b>>16);
#endif
}
__device__ __forceinline__ u32 aload(u32* p){
  return __hip_atomic_load(p, __ATOMIC_RELAXED, __HIP_MEMORY_SCOPE_AGENT);
}
__device__ __forceinline__ void astore(u32* p, u32 v){
  __hip_atomic_store(p, v, __ATOMIC_RELAXED, __HIP_MEMORY_SCOPE_AGENT);
}

// ---- pre-pass: transpose W0 (for coalesced c0 gather) ----
__global__ void k_wt(const float* __restrict__ W0, float* __restrict__ W0T){
  int tid = blockIdx.x*256 + threadIdx.x;
  if (tid < INS*WIDTH){
    int c = tid >> 11, i = tid & 2047;
    W0T[(size_t)c*WIDTH + i] = W0[(size_t)i*INS + c];
  }
}

// ---- pre-pass: W1..W4 fp32 -> fp16, thread-interleaved layout ----
// Wp[(l*2048+r)*256 + j] (uint4 = 8 halves) = W_l[r][256k+j], k=0..7
__global__ void k_wc(const float* __restrict__ A, const float* __restrict__ B,
                     const float* __restrict__ C, const float* __restrict__ D,
                     uint4* __restrict__ Wp){
  int b = blockIdx.x; int l = b >> 11; int r = b & 2047; int j = threadIdx.x;
  const float* S = (l==0)?A:(l==1)?B:(l==2)?C:D;
  const float* rowp = S + (size_t)r*WIDTH;
  u32 o[4];
  #pragma unroll
  for (int q=0;q<4;++q){
    float a = rowp[(size_t)(2*q+0)*256 + j];
    float c2= rowp[(size_t)(2*q+1)*256 + j];
    o[q] = f2h(a) | (f2h(c2) << 16);
  }
  Wp[(size_t)b*256 + j] = make_uint4(o[0],o[1],o[2],o[3]);
}

// ---- pre-pass: c0[t][i] = b0[i] + sum_m W0[i][21m + x[t-31+m]] (one-hot gather) ----
// packed as c0p[(t*256+j)] uint4 = halves for i = 256k+j, k=0..7
__global__ void k_c0(const int* __restrict__ x, const float* __restrict__ W0T,
                     const float* __restrict__ b0, uint4* __restrict__ c0p){
  int t = blockIdx.x, j = threadIdx.x;
  __shared__ int cidx[WS];
  if (j < WS){
    int s = t - (WS-1) + j;
    cidx[j] = (s >= 0) ? (NAA*j + x[s]) : -1;
  }
  __syncthreads();
  float acc[8];
  #pragma unroll
  for (int k=0;k<8;++k) acc[k] = b0[256*k + j];
  for (int m=0;m<WS;++m){
    int c = cidx[m];
    if (c >= 0){
      const float* col = W0T + (size_t)c*WIDTH;
      #pragma unroll
      for (int k=0;k<8;++k) acc[k] += col[256*k + j];
    }
  }
  u32 o[4];
  #pragma unroll
  for (int q=0;q<4;++q) o[q] = f2h(acc[2*q]) | (f2h(acc[2*q+1]) << 16);
  c0p[(size_t)t*256 + j] = make_uint4(o[0],o[1],o[2],o[3]);
}

// ---- pre-pass: reset exchange-buffer tags (re-run every launch: replay-safe) ----
__global__ void k_reset(u32* __restrict__ hb, u32* __restrict__ pb){
  int tid = blockIdx.x*256 + threadIdx.x;
  if (tid < 3*WIDTH) hb[tid] = 0xFFFFFFFFu;
  if (tid < 256)     pb[tid] = 0xFFFFFFFFu;
}

// ---- main persistent dataflow kernel ----
__global__ __launch_bounds__(256, 1) void k_main(
    const float* __restrict__ W0,
    const float* __restrict__ b1, const float* __restrict__ b2,
    const float* __restrict__ b3, const float* __restrict__ b4,
    const float* __restrict__ W5, const float* __restrict__ b5p,
    const uint4* __restrict__ Wp, const uint4* __restrict__ c0p,
    u32* __restrict__ hb, u32* __restrict__ pb, float* __restrict__ out)
{
  const int j  = threadIdx.x;
  const int X  = blockIdx.x;
  const int r8 = j & 7;
  const int row = 8*X + r8;

  __shared__ float red[4][8];
  __shared__ float redp[4];

  // one-time: W0y (window weights) into registers: w0y[k][p] = halves of
  // W0[(256k+j)][672+2p .. +1]; w31 = fp32 copy of column 31 (critical-path FMA)
  u32 w0y[8][16];
  float w31[8];
  #pragma unroll
  for (int k=0;k<8;++k){
    const float4* bp = (const float4*)(W0 + (size_t)(256*k + j)*INS + (INS - WS));
    float arr[32];
    #pragma unroll
    for (int q=0;q<8;++q){
      float4 v = bp[q];
      arr[4*q+0]=v.x; arr[4*q+1]=v.y; arr[4*q+2]=v.z; arr[4*q+3]=v.w;
    }
    #pragma unroll
    for (int p=0;p<16;++p) w0y[k][p] = f2h(arr[2*p]) | (f2h(arr[2*p+1]) << 16);
    w31[k] = arr[31];
  }
  const float w5v = W5[row];
  const float b5v = b5p[0];
  float bsc[4] = { b1[row], b2[row], b3[row], b4[row] };

  // sliding y-window as half2 pairs; slot 31 is a 0-placeholder until y[t-1] lands
  u32 yqp[16];
  #pragma unroll
  for (int p=0;p<16;++p) yqp[p] = 0u;
  float u_part[8];
  #pragma unroll
  for (int k=0;k<8;++k) u_part[k] = 0.f;

  uint4 wrow[8];
  u32 hh[4];
  const size_t LSTR = (size_t)WIDTH*256;  // uint4 per layer

  auto dolayer = [&](){
    float accv[8];
    #pragma unroll
    for (int r=0;r<8;++r){
      float a = 0.f;
      a = fdot2f(wrow[r].x, hh[0], a);
      a = fdot2f(wrow[r].y, hh[1], a);
      a = fdot2f(wrow[r].z, hh[2], a);
      a = fdot2f(wrow[r].w, hh[3], a);
      #pragma unroll
      for (int d=1; d<64; d<<=1) a += __shfl_xor(a, d);
      accv[r] = a;
    }
    if ((j & 63) == 0){
      const int w = j >> 6;
      #pragma unroll
      for (int r=0;r<8;++r) red[w][r] = accv[r];
    }
    __syncthreads();
  };

  auto pollh = [&](int l, u32 tag){
    u32 v[8];
    for(;;){
      bool ok = true;
      #pragma unroll
      for (int k=0;k<8;++k){
        v[k] = aload(&hb[l*WIDTH + 256*k + j]);
        ok &= ((v[k] >> 16) == tag);
      }
      if (ok) break;
    }
    #pragma unroll
    for (int q=0;q<4;++q) hh[q] = (v[2*q] & 0xffffu) | (v[2*q+1] << 16);
  };

  #pragma unroll 1
  for (int t=0; t<L_SEQ; ++t){
    // prefetch layer-1 rows + c0 chunk (in flight during phase A)
    #pragma unroll
    for (int r=0;r<8;++r) wrow[r] = Wp[(size_t)(8*X + r)*256 + j];
    uint4 c0v = c0p[(size_t)t*256 + j];

    // ---- phase A: gather partials, everyone redundantly computes y[t-1] ----
    float yprev = 0.f;
    if (t > 0){
      u32 pv;
      do { pv = aload(&pb[j]); } while ((pv >> 16) != (u32)(t-1));
      float p = h2f(pv);
      #pragma unroll
      for (int d=1; d<64; d<<=1) p += __shfl_xor(p, d);
      if ((j & 63) == 0) redp[j >> 6] = p;
      __syncthreads();
      float y = fmaxf(redp[0]+redp[1]+redp[2]+redp[3] + b5v, 0.f);
      if (X == 0 && j == 0) out[t-1] = y;
      yprev = y;
      yqp[15] |= (f2h(y) << 16);   // complete the window for step t
    }

    // h0 chunk = relu(c0 + u_part + w31*y[t-1]); pack to half2 pairs
    {
      u32 c0h[4] = { c0v.x, c0v.y, c0v.z, c0v.w };
      float h0v[8];
      #pragma unroll
      for (int k=0;k<8;++k){
        u32 cb = (k & 1) ? (c0h[k>>1] >> 16) : c0h[k>>1];
        h0v[k] = fmaxf(h2f(cb) + u_part[k] + w31[k]*yprev, 0.f);
      }
      #pragma unroll
      for (int q=0;q<4;++q) hh[q] = f2h(h0v[2*q]) | (f2h(h0v[2*q+1]) << 16);
    }

    // ---- layer 1 ----
    dolayer();
    if (j < 8){
      float s = fmaxf(red[0][j]+red[1][j]+red[2][j]+red[3][j] + bsc[0], 0.f);
      astore(&hb[0*WIDTH + row], ((u32)t << 16) | f2h(s));
    }
    __syncthreads();
    #pragma unroll
    for (int r=0;r<8;++r) wrow[r] = Wp[LSTR + (size_t)(8*X + r)*256 + j];
    // off-critical-path: slide window (slot31 := 0) and precompute u_part(t+1)
    {
      #pragma unroll
      for (int p=0;p<15;++p) yqp[p] = (yqp[p] >> 16) | (yqp[p+1] << 16);
      yqp[15] = (yqp[15] >> 16);
      #pragma unroll
      for (int k=0;k<8;++k){
        float a = 0.f;
        #pragma unroll
        for (int p=0;p<16;++p) a = fdot2f(w0y[k][p], yqp[p], a);
        u_part[k] = a;
      }
    }
    pollh(0, (u32)t);

    // ---- layer 2 ----
    dolayer();
    if (j < 8){
      float s = fmaxf(red[0][j]+red[1][j]+red[2][j]+red[3][j] + bsc[1], 0.f);
      astore(&hb[1*WIDTH + row], ((u32)t << 16) | f2h(s));
    }
    __syncthreads();
    #pragma unroll
    for (int r=0;r<8;++r) wrow[r] = Wp[2*LSTR + (size_t)(8*X + r)*256 + j];
    pollh(1, (u32)t);

    // ---- layer 3 ----
    dolayer();
    if (j < 8){
      float s = fmaxf(red[0][j]+red[1][j]+red[2][j]+red[3][j] + bsc[2], 0.f);
      astore(&hb[2*WIDTH + row], ((u32)t << 16) | f2h(s));
    }
    __syncthreads();
    #pragma unroll
    for (int r=0;r<8;++r) wrow[r] = Wp[3*LSTR + (size_t)(8*X + r)*256 + j];
    pollh(2, (u32)t);

    // ---- layer 4 + W5 partial (h4 never exchanged) ----
    dolayer();
    if (j < 8){
      float s = fmaxf(red[0][j]+red[1][j]+red[2][j]+red[3][j] + bsc[3], 0.f);
      float pp = s * w5v;
      pp += __shfl_xor(pp, 1);
      pp += __shfl_xor(pp, 2);
      pp += __shfl_xor(pp, 4);
      if (j == 0) astore(&pb[X], ((u32)t << 16) | f2h(pp));
    }
    // red[] reuse is ordered by the phase-A __syncthreads of iteration t+1
  }

  // epilogue: y[L-1]
  if (X == 0){
    u32 pv;
    do { pv = aload(&pb[j]); } while ((pv >> 16) != (u32)(L_SEQ-1));
    float p = h2f(pv);
    #pragma unroll
    for (int d=1; d<64; d<<=1) p += __shfl_xor(p, d);
    if ((j & 63) == 0) redp[j >> 6] = p;
    __syncthreads();
    if (j == 0) out[L_SEQ-1] = fmaxf(redp[0]+redp[1]+redp[2]+redp[3] + b5v, 0.f);
  }
}

extern "C" void kernel_launch(void* const* d_in, const int* in_sizes, int n_in,
                              void* d_out, int out_size, void* d_ws, size_t ws_size,
                              hipStream_t stream) {
  (void)in_sizes; (void)n_in; (void)out_size; (void)ws_size;
  const int*   x  = (const int*)  d_in[0];
  const float* W0 = (const float*)d_in[1];
  const float* b0 = (const float*)d_in[2];
  const float* W1 = (const float*)d_in[3];
  const float* b1 = (const float*)d_in[4];
  const float* W2 = (const float*)d_in[5];
  const float* b2 = (const float*)d_in[6];
  const float* W3 = (const float*)d_in[7];
  const float* b3 = (const float*)d_in[8];
  const float* W4 = (const float*)d_in[9];
  const float* b4 = (const float*)d_in[10];
  const float* W5 = (const float*)d_in[11];
  const float* b5 = (const float*)d_in[12];
  float* out = (float*)d_out;
  char*  ws  = (char*)d_ws;

  // ws layout (all 16B-aligned), total ~45.5 MB
  constexpr size_t OFF_WP  = 0;                       // 4*2048*256*16 = 33,554,432
  constexpr size_t OFF_C0  = 33554432;                // 2048*256*16   =  8,388,608
  constexpr size_t OFF_W0T = 41943040;                // 704*2048*4    =  5,767,168
  constexpr size_t OFF_HB  = 47710208;                // 3*2048*4      =     24,576
  constexpr size_t OFF_PB  = 47734784;                // 256*4         =      1,024

  uint4* Wp  = (uint4*)(ws + OFF_WP);
  uint4* c0p = (uint4*)(ws + OFF_C0);
  float* W0T = (float*)(ws + OFF_W0T);
  u32*   hb  = (u32*)  (ws + OFF_HB);
  u32*   pb  = (u32*)  (ws + OFF_PB);

  k_wt   <<<5632, 256, 0, stream>>>(W0, W0T);
  k_wc   <<<8192, 256, 0, stream>>>(W1, W2, W3, W4, Wp);
  k_c0   <<<2048, 256, 0, stream>>>(x, W0T, b0, c0p);
  k_reset<<<24,   256, 0, stream>>>(hb, pb);
  k_main <<<256,  256, 0, stream>>>(W0, b1, b2, b3, b4, W5, b5,
                                    Wp, c0p, hb, pb, out);
}